// Round 5
// baseline (914.195 us; speedup 1.0000x reference)
//
#include <hip/hip_runtime.h>

typedef unsigned short u16;
typedef unsigned int u32;
typedef __bf16 bf16x8 __attribute__((ext_vector_type(8)));
typedef float f32x4 __attribute__((ext_vector_type(4)));

#define NN 2048      // nodes
#define NE 6144      // edges
#define DVIN 128
#define DVOUT 64
#define DEIN 16
#define DEOUT 16

#define BM 128
#define BN 128
#define MS 132       // mirror LDS row stride (u16), pad to break bank conflicts

__device__ __forceinline__ u16 f2b(float f) {
  __bf16 b = (__bf16)f;
  return __builtin_bit_cast(u16, b);
}

__device__ __forceinline__ float b2f(u16 u) {
  return __uint_as_float(((u32)u) << 16);
}

__device__ __forceinline__ bf16x8 load8(const u16* p) {
  union { uint4 u; bf16x8 b; } w;
  w.u = *(const uint4*)p;
  return w.b;
}

// dense upper-triangle decode: L = bi*Nt - bi*(bi-1)/2 + (bj-bi), bi<=bj
__device__ __forceinline__ void tri_decode(int L, int Nt, int& bi, int& bj) {
  float Nf = (float)Nt + 0.5f;
  int b = (int)(Nf - sqrtf(Nf * Nf - 2.0f * (float)L));
  while (b * Nt - (b * (b - 1)) / 2 > L) b--;
  while ((b + 1) * Nt - ((b + 1) * b) / 2 <= L) b++;
  bi = b;
  bj = b + (L - (b * Nt - (b * (b - 1)) / 2));
}

// ---------------- small kernels ----------------

__global__ __launch_bounds__(256) void k_de(const float* __restrict__ He,
                                            const float* __restrict__ pv,
                                            float* __restrict__ de) {
  int j = blockIdx.x * 256 + threadIdx.x;
  float s = 0.f;
#pragma unroll
  for (int k = 0; k < DEIN; k++) s += He[j * DEIN + k] * pv[k];
  de[j] = s;
}

__global__ __launch_bounds__(256) void k_tb(const float* __restrict__ T,
                                            const float* __restrict__ de,
                                            u16* __restrict__ Tb,
                                            u16* __restrict__ Tbs) {
  size_t idx = (size_t)blockIdx.x * 256 + threadIdx.x;
  size_t f = idx * 8;
  float4 v0 = *(const float4*)(T + f);
  float4 v1 = *(const float4*)(T + f + 4);
  int col = (int)(f % (size_t)NE);
  float4 d0 = *(const float4*)(de + col);
  float4 d1 = *(const float4*)(de + col + 4);
  float v[8] = {v0.x, v0.y, v0.z, v0.w, v1.x, v1.y, v1.z, v1.w};
  float d[8] = {d0.x, d0.y, d0.z, d0.w, d1.x, d1.y, d1.z, d1.w};
  union { u16 s[8]; uint4 u; } a, b;
#pragma unroll
  for (int j = 0; j < 8; j++) { a.s[j] = f2b(v[j]); b.s[j] = f2b(v[j] * d[j]); }
  *(uint4*)(Tb + f) = a.u;
  *(uint4*)(Tbs + f) = b.u;
}

__global__ __launch_bounds__(256) void k_x(const float* __restrict__ Hv,
                                           const float* __restrict__ Wv,
                                           u16* __restrict__ Xt) {
  int i = blockIdx.x * 256 + threadIdx.x;
  int d = blockIdx.y;
  float s = 0.f;
#pragma unroll 8
  for (int k = 0; k < DVIN; k++) s += Hv[i * DVIN + k] * Wv[k * DVOUT + d];
  Xt[(size_t)d * NN + i] = f2b(s);
}

__global__ __launch_bounds__(256) void k_dv(const float* __restrict__ HvOut,
                                            const float* __restrict__ pe,
                                            float* __restrict__ dv) {
  int i = blockIdx.x * 256 + threadIdx.x;
  float s = 0.f;
#pragma unroll
  for (int c = 0; c < DVOUT; c++) s += HvOut[i * DVOUT + c] * pe[c];
  dv[i] = s;
}

__global__ __launch_bounds__(256) void k_tt(const float* __restrict__ T,
                                            const float* __restrict__ dv,
                                            u16* __restrict__ Tt,
                                            u16* __restrict__ Tts) {
  __shared__ float tile[32][33];
  int tx = threadIdx.x, ty = threadIdx.y;
  int bx = blockIdx.x, by = blockIdx.y;
  int col = bx * 32 + tx;
#pragma unroll
  for (int r = 0; r < 4; r++) {
    int row = by * 32 + ty + r * 8;
    tile[ty + r * 8][tx] = T[(size_t)row * NE + col];
  }
  __syncthreads();
  int ocol = by * 32 + tx;
  float dvv = dv[ocol];
#pragma unroll
  for (int r = 0; r < 4; r++) {
    int orow = bx * 32 + ty + r * 8;
    float v = tile[tx][ty + r * 8];
    Tt[(size_t)orow * NN + ocol] = f2b(v);
    Tts[(size_t)orow * NN + ocol] = f2b(v * dvv);
  }
}

__global__ __launch_bounds__(256) void k_zt(const float* __restrict__ He,
                                            const float* __restrict__ We,
                                            const u32* __restrict__ colmax,
                                            u16* __restrict__ Ztb) {
  int b = blockIdx.x * 256 + threadIdx.x;
  float h[16];
  const float4* hp = (const float4*)(He + (size_t)b * DEIN);
#pragma unroll
  for (int q = 0; q < 4; q++) {
    float4 t = hp[q];
    h[q * 4 + 0] = t.x; h[q * 4 + 1] = t.y; h[q * 4 + 2] = t.z; h[q * 4 + 3] = t.w;
  }
  float inv = 1.0f / (__uint_as_float(colmax[b]) + 1e-10f);
#pragma unroll
  for (int d = 0; d < DEOUT; d++) {
    float s = 0.f;
#pragma unroll
    for (int k = 0; k < DEIN; k++) s += h[k] * We[k * DEOUT + d];
    Ztb[(size_t)d * NE + b] = f2b(s * inv);
  }
}

// ---------------- direct-streaming MFMA K-loop: no LDS, no barriers ----------------
// Fragments load straight from global (L2/L3-resident operands) into VGPRs.
// Latency hidden by TLP (4 blocks/CU) + compiler scheduling, not barriers.
__device__ __forceinline__ void tile_loop_direct(const u16* __restrict__ A,
                                                 const u16* __restrict__ B,
                                                 int bm0, int bn0, int K,
                                                 int kbeg, int kend,
                                                 f32x4 (&acc)[4][4]) {
  const int t = threadIdx.x;
  const int lane = t & 63;
  const int lr = lane & 15, kg = lane >> 4;
  const int wave = t >> 6;
  const int wm = (wave >> 1) * 64, wn = (wave & 1) * 64;

  const u16* Ab = A + (size_t)(bm0 + wm + lr) * K + kg * 8;
  const u16* Bb = B + (size_t)(bn0 + wn + lr) * K + kg * 8;
  const size_t R16 = (size_t)16 * K;

#pragma unroll 2
  for (int k = kbeg; k < kend; k += 32) {
    bf16x8 af[4], bf[4];
#pragma unroll
    for (int mi = 0; mi < 4; mi++) af[mi] = load8(Ab + mi * R16 + k);
#pragma unroll
    for (int ni = 0; ni < 4; ni++) bf[ni] = load8(Bb + ni * R16 + k);
#pragma unroll
    for (int mi = 0; mi < 4; mi++)
#pragma unroll
      for (int ni = 0; ni < 4; ni++)
        acc[mi][ni] = __builtin_amdgcn_mfma_f32_16x16x32_bf16(
            af[mi], bf[ni], acc[mi][ni], 0, 0, 0);
  }
}

// ---------------- node layer: dense-triangular symmetric + split-K ----------------
// grid.x = 544 = 8 XCD-chunks of 68. P stored block-linear, scrambled
// per-thread layout (fully coalesced float4 stores).
__global__ __launch_bounds__(256) void gemm_sym1(const u16* __restrict__ A,
                                                 const u16* __restrict__ B,
                                                 float* __restrict__ P) {
  const int L0 = blockIdx.x;
  const int L = (L0 & 7) * 68 + (L0 >> 3);  // XCD-chunked order
  const int z = L / 136, tri = L - z * 136;
  int bi, bj;
  tri_decode(tri, NN / BM, bi, bj);
  const int bm0 = bi * BM, bn0 = bj * BN;
  const int kc = NE / 4;
  f32x4 acc[4][4];
#pragma unroll
  for (int i = 0; i < 4; i++)
#pragma unroll
    for (int j = 0; j < 4; j++) acc[i][j] = (f32x4){0.f, 0.f, 0.f, 0.f};

  tile_loop_direct(A, B, bm0, bn0, NE, z * kc, (z + 1) * kc, acc);

  const int t = threadIdx.x;
  f32x4* P4 = (f32x4*)(P + ((size_t)z * 136 + tri) * (BM * BN) + t * 64);
#pragma unroll
  for (int ni = 0; ni < 4; ni++)
#pragma unroll
    for (int mi = 0; mi < 4; mi++) P4[ni * 4 + mi] = acc[mi][ni];
}

// combine: sum 4 scrambled P slices -> LDS tile -> A1 both triangles
__global__ __launch_bounds__(256) void k_comb(const float* __restrict__ P,
                                              const float* __restrict__ adj,
                                              u16* __restrict__ A1) {
  const int tri = blockIdx.x;
  int bi, bj;
  tri_decode(tri, NN / BM, bi, bj);
  __shared__ float tile[128][129];
  const int bm0 = bi * 128, bn0 = bj * 128;
  const int t = threadIdx.x;
  const bool diagb = (bi == bj);
  const int lane = t & 63, lr = lane & 15, kg = lane >> 4;
  const int wave = t >> 6, wm = (wave >> 1) * 64, wn = (wave & 1) * 64;

  const f32x4* P4 = (const f32x4*)(P + (size_t)tri * (BM * BN) + t * 64);
  const size_t SL = (size_t)136 * BM * BN / 4;  // slice stride in f32x4 units
#pragma unroll
  for (int ni = 0; ni < 4; ni++) {
#pragma unroll
    for (int mi = 0; mi < 4; mi++) {
      f32x4 s = P4[ni * 4 + mi];
      f32x4 s1 = P4[SL + ni * 4 + mi];
      f32x4 s2 = P4[2 * SL + ni * 4 + mi];
      f32x4 s3 = P4[3 * SL + ni * 4 + mi];
      s = s + s1 + s2 + s3;
      const int cil = wm + mi * 16 + kg * 4;
      const int cjl = wn + ni * 16 + lr;
#pragma unroll
      for (int r = 0; r < 4; r++) tile[cil + r][cjl] = s[r];
    }
  }
  __syncthreads();
  for (int e = t; e < 128 * 32; e += 256) {
    int row = e >> 5, c4 = (e & 31) * 4;
    size_t off = (size_t)(bm0 + row) * NN + bn0 + c4;
    float4 av = *(const float4*)(adj + off);
    float avv[4] = {av.x, av.y, av.z, av.w};
    union { u16 h[4]; uint2 u; } o;
#pragma unroll
    for (int q = 0; q < 4; q++) {
      float sv = tile[row][c4 + q];
      if (diagb && (c4 + q == row)) sv = 1.0f;
      o.h[q] = f2b(sv * avv[q]);
    }
    *(uint2*)(A1 + off) = o.u;
  }
  if (!diagb) {
    for (int e = t; e < 128 * 32; e += 256) {
      int row = e >> 5, c4 = (e & 31) * 4;
      size_t off = (size_t)(bn0 + row) * NN + bm0 + c4;
      float4 av = *(const float4*)(adj + off);
      float avv[4] = {av.x, av.y, av.z, av.w};
      union { u16 h[4]; uint2 u; } o;
#pragma unroll
      for (int q = 0; q < 4; q++) o.h[q] = f2b(tile[c4 + q][row] * avv[q]);
      *(uint2*)(A1 + off) = o.u;
    }
  }
}

// ---------------- edge layer: dense-triangular symmetric, bf16 out + colmax ----------------
__global__ __launch_bounds__(256) void gemm_sym2(const u16* __restrict__ A,
                                                 const u16* __restrict__ B,
                                                 const float* __restrict__ adj,
                                                 u16* __restrict__ C,
                                                 u32* __restrict__ colmax) {
  const int TB2 = (NE / BM) * (NE / BM + 1) / 2;  // 1176 = 8 * 147
  const int L = (blockIdx.x & 7) * (TB2 / 8) + (blockIdx.x >> 3);
  int bi, bj;
  tri_decode(L, NE / BM, bi, bj);
  __shared__ u16 mir[128 * MS];
  __shared__ u32 cmaxN[128];
  __shared__ u32 cmaxM[128];
  const int bm0 = bi * BM, bn0 = bj * BN;
  const int t = threadIdx.x;
  const int N = NE, K = NN;
  const bool diagb = (bi == bj);
  if (t < 128) { cmaxN[t] = 0u; cmaxM[t] = 0u; }

  f32x4 acc[4][4];
#pragma unroll
  for (int i = 0; i < 4; i++)
#pragma unroll
    for (int j = 0; j < 4; j++) acc[i][j] = (f32x4){0.f, 0.f, 0.f, 0.f};

  tile_loop_direct(A, B, bm0, bn0, K, 0, K, acc);

  const int lane = t & 63, lr = lane & 15, kg = lane >> 4;
  const int wave = t >> 6, wm = (wave >> 1) * 64, wn = (wave & 1) * 64;

  __syncthreads();  // cmax LDS init visible to all waves before atomics

#pragma unroll
  for (int ni = 0; ni < 4; ni++) {
    const int cjl = wn + ni * 16 + lr;
    const int cj = bn0 + cjl;
    float cm = 0.f;
#pragma unroll
    for (int mi = 0; mi < 4; mi++) {
#pragma unroll
      for (int r = 0; r < 4; r++) {
        const int cil = wm + mi * 16 + kg * 4 + r;
        const int ci = bm0 + cil;
        float v = acc[mi][ni][r];
        if (ci == cj) v = 1.0f;
        float w = v * adj[(size_t)ci * N + cj];
        C[(size_t)ci * N + cj] = f2b(w);
        cm = fmaxf(cm, w);
        if (!diagb) mir[cjl * MS + cil] = f2b(v);
      }
    }
    atomicMax(&cmaxN[cjl], __float_as_uint(cm));
  }

  if (!diagb) {
    __syncthreads();
    const int rb = t >> 4, cb = (t & 15) * 8;
    float rmax[8];
#pragma unroll
    for (int q = 0; q < 8; q++) rmax[q] = 0.f;
#pragma unroll
    for (int rr = 0; rr < 8; rr++) {
      const int row = rb + rr * 16;
      union { uint2 u; u16 s[4]; } w0, w1;
      w0.u = *(const uint2*)&mir[row * MS + cb];
      w1.u = *(const uint2*)&mir[row * MS + cb + 4];
      float f[8] = {b2f(w0.s[0]), b2f(w0.s[1]), b2f(w0.s[2]), b2f(w0.s[3]),
                    b2f(w1.s[0]), b2f(w1.s[1]), b2f(w1.s[2]), b2f(w1.s[3])};
      const float* ap = adj + (size_t)(bn0 + row) * N + bm0 + cb;
      float4 a0 = *(const float4*)ap;
      float4 a1 = *(const float4*)(ap + 4);
      float a[8] = {a0.x, a0.y, a0.z, a0.w, a1.x, a1.y, a1.z, a1.w};
      union { u16 s[8]; uint4 u; } o;
#pragma unroll
      for (int q = 0; q < 8; q++) {
        float w = f[q] * a[q];
        rmax[q] = fmaxf(rmax[q], w);
        o.s[q] = f2b(w);
      }
      *(uint4*)&C[(size_t)(bn0 + row) * N + bm0 + cb] = o.u;
    }
#pragma unroll
    for (int q = 0; q < 8; q++)
      atomicMax(&cmaxM[cb + q], __float_as_uint(rmax[q]));
  }

  __syncthreads();
  if (t < 128) {
    atomicMax(&colmax[bn0 + t], cmaxN[t]);
    if (!diagb) atomicMax(&colmax[bm0 + t], cmaxM[t]);
  }
}

// ---------------- thin MFMA gemms (8 waves/block for latency hiding) ----------------

__global__ __launch_bounds__(512) void k_hv(const u16* __restrict__ A1,
                                            const u16* __restrict__ Xt,
                                            const float* __restrict__ bv,
                                            float* __restrict__ out) {
  __shared__ float red[8 * 1024];
  const int t = threadIdx.x, wave = t >> 6, lane = t & 63;
  const int lr = lane & 15, kg = lane >> 4;
  const int m0 = blockIdx.x * 16;
  const int K = NN;
  f32x4 acc[4];
#pragma unroll
  for (int i = 0; i < 4; i++) acc[i] = (f32x4){0.f, 0.f, 0.f, 0.f};
  const int kbeg = wave * (K / 8), kend = kbeg + (K / 8);
  for (int k = kbeg; k < kend; k += 32) {
    bf16x8 af = load8(&A1[(size_t)(m0 + lr) * K + k + kg * 8]);
#pragma unroll
    for (int ni = 0; ni < 4; ni++) {
      bf16x8 bfr = load8(&Xt[(size_t)(ni * 16 + lr) * K + k + kg * 8]);
      acc[ni] = __builtin_amdgcn_mfma_f32_16x16x32_bf16(af, bfr, acc[ni], 0, 0, 0);
    }
  }
#pragma unroll
  for (int ni = 0; ni < 4; ni++)
#pragma unroll
    for (int r = 0; r < 4; r++)
      red[wave * 1024 + (kg * 4 + r) * 64 + ni * 16 + lr] = acc[ni][r];
  __syncthreads();
#pragma unroll
  for (int q = 0; q < 2; q++) {
    int e = t + 512 * q;
    int row = e >> 6, col = e & 63;
    float v = bv[col];
#pragma unroll
    for (int w = 0; w < 8; w++) v += red[w * 1024 + e];
    out[(size_t)(m0 + row) * DVOUT + col] = v;
  }
}

__global__ __launch_bounds__(512) void k_he(const u16* __restrict__ adjE,
                                            const u16* __restrict__ Ztb,
                                            const float* __restrict__ be,
                                            float* __restrict__ out) {
  __shared__ float red[8 * 256];
  const int t = threadIdx.x, wave = t >> 6, lane = t & 63;
  const int lr = lane & 15, kg = lane >> 4;
  const int m0 = blockIdx.x * 16;
  const int K = NE;
  f32x4 acc = (f32x4){0.f, 0.f, 0.f, 0.f};
  const int kbeg = wave * (K / 8), kend = kbeg + (K / 8);
  for (int k = kbeg; k < kend; k += 32) {
    bf16x8 af = load8(&adjE[(size_t)(m0 + lr) * K + k + kg * 8]);
    bf16x8 bfr = load8(&Ztb[(size_t)lr * K + k + kg * 8]);
    acc = __builtin_amdgcn_mfma_f32_16x16x32_bf16(af, bfr, acc, 0, 0, 0);
  }
#pragma unroll
  for (int r = 0; r < 4; r++)
    red[wave * 256 + (kg * 4 + r) * 16 + lr] = acc[r];
  __syncthreads();
  if (t < 256) {
    int row = t >> 4, col = t & 15;
    float v = be[col];
#pragma unroll
    for (int w = 0; w < 8; w++) v += red[w * 256 + t];
    out[(size_t)(m0 + row) * DEOUT + col] = v;
  }
}

// ---------------- launcher ----------------
extern "C" void kernel_launch(void* const* d_in, const int* in_sizes, int n_in,
                              void* d_out, int out_size, void* d_ws, size_t ws_size,
                              hipStream_t stream) {
  const float* H_v = (const float*)d_in[0];
  const float* H_e = (const float*)d_in[1];
  const float* adj_v = (const float*)d_in[2];
  const float* adj_e = (const float*)d_in[3];
  const float* T = (const float*)d_in[4];
  const float* W_v = (const float*)d_in[5];
  const float* b_v = (const float*)d_in[6];
  const float* p_v = (const float*)d_in[7];
  const float* W_e = (const float*)d_in[8];
  const float* b_e = (const float*)d_in[9];
  const float* p_e = (const float*)d_in[10];
  float* outHv = (float*)d_out;              // [2048,64]
  float* outHe = (float*)d_out + NN * DVOUT; // [6144,16]

  char* ws = (char*)d_ws;
  u16* Tb   = (u16*)(ws + 0);           // 25165824
  u16* Tbs  = (u16*)(ws + 25165824);    // 25165824
  u16* Tt   = (u16*)(ws + 50331648);    // 25165824
  u16* Tts  = (u16*)(ws + 75497472);    // 25165824
  u16* adjE = (u16*)(ws + 100663296);   // 75497472
  u16* A1   = (u16*)(ws + 176160768);   // 8388608
  u16* Xt   = (u16*)(ws + 184549376);   // 262144
  u16* Ztb  = (u16*)(ws + 184811520);   // 196608
  float* de = (float*)(ws + 185008128); // 24576
  float* dv = (float*)(ws + 185032704); // 8192
  u32* cmax = (u32*)(ws + 185040896);   // 24576
  // P (split-K fp32 partials, 4*136*16384*4 = 35,651,584 B) at offset
  // 50331648, OVERLAPPING Tt/Tts/adjE: P is dead after k_comb, which runs
  // before k_tt / gemm_sym2 write those buffers.
  float* P = (float*)(ws + 50331648);

  k_de<<<NE / 256, 256, 0, stream>>>(H_e, p_v, de);
  k_tb<<<(NN * (size_t)NE) / 8 / 256, 256, 0, stream>>>(T, de, Tb, Tbs);
  k_x<<<dim3(NN / 256, DVOUT), 256, 0, stream>>>(H_v, W_v, Xt);
  gemm_sym1<<<4 * 136, 256, 0, stream>>>(Tbs, Tb, P);
  k_comb<<<136, 256, 0, stream>>>(P, adj_v, A1);
  k_hv<<<NN / 16, 512, 0, stream>>>(A1, Xt, b_v, outHv);
  k_dv<<<NN / 256, 256, 0, stream>>>(outHv, p_e, dv);
  k_tt<<<dim3(NE / 32, NN / 32), dim3(32, 8), 0, stream>>>(T, dv, Tt, Tts);
  hipMemsetAsync(cmax, 0, NE * sizeof(u32), stream);
  gemm_sym2<<<(NE / BM) * (NE / BM + 1) / 2, 256, 0, stream>>>(
      Tts, Tt, adj_e, adjE, cmax);
  k_zt<<<NE / 256, 256, 0, stream>>>(H_e, W_e, cmax, Ztb);
  k_he<<<NE / 16, 512, 0, stream>>>(adjE, Ztb, b_e, outHe);
}

// Round 6
// 563.911 us; speedup vs baseline: 1.6212x; 1.6212x over previous
//
#include <hip/hip_runtime.h>

typedef unsigned short u16;
typedef unsigned int u32;
typedef __bf16 bf16x8 __attribute__((ext_vector_type(8)));
typedef float f32x4 __attribute__((ext_vector_type(4)));

#define NN 2048      // nodes
#define NE 6144      // edges
#define DVIN 128
#define DVOUT 64
#define DEIN 16
#define DEOUT 16

// edge-layer GEMM tile
#define T2 96
#define NT2 (NE / T2)                 // 64
#define NB2 (NT2 * (NT2 + 1) / 2)     // 2080
#define MS2 100                       // mirror LDS row stride (u16)
// node-layer GEMM tile
#define T1 64
#define NT1 (NN / T1)                 // 32
#define NB1 (NT1 * (NT1 + 1) / 2)     // 528

__device__ __forceinline__ u16 f2b(float f) {
  __bf16 b = (__bf16)f;
  return __builtin_bit_cast(u16, b);
}

__device__ __forceinline__ float b2f(u16 u) {
  return __uint_as_float(((u32)u) << 16);
}

__device__ __forceinline__ void async16(const void* g, void* l) {
  __builtin_amdgcn_global_load_lds(
      (const __attribute__((address_space(1))) void*)g,
      (__attribute__((address_space(3))) void*)l, 16, 0, 0);
}

__device__ __forceinline__ bf16x8 load8(const u16* p) {
  union { uint4 u; bf16x8 b; } w;
  w.u = *(const uint4*)p;
  return w.b;
}

// dense upper-triangle decode: L = bi*Nt - bi*(bi-1)/2 + (bj-bi), bi<=bj
__device__ __forceinline__ void tri_decode(int L, int Nt, int& bi, int& bj) {
  float Nf = (float)Nt + 0.5f;
  int b = (int)(Nf - sqrtf(Nf * Nf - 2.0f * (float)L));
  while (b * Nt - (b * (b - 1)) / 2 > L) b--;
  while ((b + 1) * Nt - ((b + 1) * b) / 2 <= L) b++;
  bi = b;
  bj = b + (L - (b * Nt - (b * (b - 1)) / 2));
}

// ---------------- small kernels ----------------

__global__ __launch_bounds__(256) void k_de(const float* __restrict__ He,
                                            const float* __restrict__ pv,
                                            float* __restrict__ de) {
  int j = blockIdx.x * 256 + threadIdx.x;
  float s = 0.f;
#pragma unroll
  for (int k = 0; k < DEIN; k++) s += He[j * DEIN + k] * pv[k];
  de[j] = s;
}

__global__ __launch_bounds__(256) void k_tb(const float* __restrict__ T,
                                            const float* __restrict__ de,
                                            u16* __restrict__ Tb,
                                            u16* __restrict__ Tbs) {
  size_t idx = (size_t)blockIdx.x * 256 + threadIdx.x;
  size_t f = idx * 8;
  float4 v0 = *(const float4*)(T + f);
  float4 v1 = *(const float4*)(T + f + 4);
  int col = (int)(f % (size_t)NE);
  float4 d0 = *(const float4*)(de + col);
  float4 d1 = *(const float4*)(de + col + 4);
  float v[8] = {v0.x, v0.y, v0.z, v0.w, v1.x, v1.y, v1.z, v1.w};
  float d[8] = {d0.x, d0.y, d0.z, d0.w, d1.x, d1.y, d1.z, d1.w};
  union { u16 s[8]; uint4 u; } a, b;
#pragma unroll
  for (int j = 0; j < 8; j++) { a.s[j] = f2b(v[j]); b.s[j] = f2b(v[j] * d[j]); }
  *(uint4*)(Tb + f) = a.u;
  *(uint4*)(Tbs + f) = b.u;
}

__global__ __launch_bounds__(256) void k_x(const float* __restrict__ Hv,
                                           const float* __restrict__ Wv,
                                           u16* __restrict__ Xt) {
  int i = blockIdx.x * 256 + threadIdx.x;
  int d = blockIdx.y;
  float s = 0.f;
#pragma unroll 8
  for (int k = 0; k < DVIN; k++) s += Hv[i * DVIN + k] * Wv[k * DVOUT + d];
  Xt[(size_t)d * NN + i] = f2b(s);
}

__global__ __launch_bounds__(256) void k_dv(const float* __restrict__ HvOut,
                                            const float* __restrict__ pe,
                                            float* __restrict__ dv) {
  int i = blockIdx.x * 256 + threadIdx.x;
  float s = 0.f;
#pragma unroll
  for (int c = 0; c < DVOUT; c++) s += HvOut[i * DVOUT + c] * pe[c];
  dv[i] = s;
}

__global__ __launch_bounds__(256) void k_tt(const float* __restrict__ T,
                                            const float* __restrict__ dv,
                                            u16* __restrict__ Tt,
                                            u16* __restrict__ Tts) {
  __shared__ float tile[32][33];
  int tx = threadIdx.x, ty = threadIdx.y;
  int bx = blockIdx.x, by = blockIdx.y;
  int col = bx * 32 + tx;
#pragma unroll
  for (int r = 0; r < 4; r++) {
    int row = by * 32 + ty + r * 8;
    tile[ty + r * 8][tx] = T[(size_t)row * NE + col];
  }
  __syncthreads();
  int ocol = by * 32 + tx;
  float dvv = dv[ocol];
#pragma unroll
  for (int r = 0; r < 4; r++) {
    int orow = bx * 32 + ty + r * 8;
    float v = tile[tx][ty + r * 8];
    Tt[(size_t)orow * NN + ocol] = f2b(v);
    Tts[(size_t)orow * NN + ocol] = f2b(v * dvv);
  }
}

__global__ __launch_bounds__(256) void k_zt(const float* __restrict__ He,
                                            const float* __restrict__ We,
                                            const u32* __restrict__ colmax,
                                            u16* __restrict__ Ztb) {
  int b = blockIdx.x * 256 + threadIdx.x;
  float h[16];
  const float4* hp = (const float4*)(He + (size_t)b * DEIN);
#pragma unroll
  for (int q = 0; q < 4; q++) {
    float4 t = hp[q];
    h[q * 4 + 0] = t.x; h[q * 4 + 1] = t.y; h[q * 4 + 2] = t.z; h[q * 4 + 3] = t.w;
  }
  float inv = 1.0f / (__uint_as_float(colmax[b]) + 1e-10f);
#pragma unroll
  for (int d = 0; d < DEOUT; d++) {
    float s = 0.f;
#pragma unroll
    for (int k = 0; k < DEIN; k++) s += h[k] * We[k * DEOUT + d];
    Ztb[(size_t)d * NE + b] = f2b(s * inv);
  }
}

// init outputs with biases (k_hv/k_he atomicAdd partial sums on top)
__global__ __launch_bounds__(256) void k_bias(const float* __restrict__ bv,
                                              const float* __restrict__ be,
                                              float* __restrict__ outHv,
                                              float* __restrict__ outHe) {
  int i = blockIdx.x * 256 + threadIdx.x;
  if (i < NN * DVOUT) {
    outHv[i] = bv[i & 63];
  } else {
    int j = i - NN * DVOUT;
    outHe[j] = be[j & 15];
  }
}

// ---------------- node layer: 64x64 dense-triangular + split-K=3 ----------------
// grid 1584 = 8 XCD chunks of 198. wave w: 32x32 subtile.
__global__ __launch_bounds__(256) void gemm_sym1(const u16* __restrict__ A,
                                                 const u16* __restrict__ B,
                                                 float* __restrict__ P) {
  const int Ls = (blockIdx.x & 7) * 198 + (blockIdx.x >> 3);
  const int z = Ls / NB1, tri = Ls - z * NB1;
  int bi, bj;
  tri_decode(tri, NT1, bi, bj);
  __shared__ u16 As[T1 * 64];
  __shared__ u16 Bs[T1 * 64];
  const int bm0 = bi * T1, bn0 = bj * T1;
  const int t = threadIdx.x, lane = t & 63;
  const int lr = lane & 15, kg = lane >> 4;
  const int wave = t >> 6;
  const int wm = (wave >> 1) * 32, wn = (wave & 1) * 32;
  const int K = NE;
  const int kbeg = z * 2048, kend = kbeg + 2048;

  f32x4 acc[2][2];
#pragma unroll
  for (int i = 0; i < 2; i++)
#pragma unroll
    for (int j = 0; j < 2; j++) acc[i][j] = (f32x4){0.f, 0.f, 0.f, 0.f};

  const int arow = t >> 3;
  const int acolsw = (((t & 7) ^ (arow & 7)) * 8);
  const u16* Ag = A + (size_t)(bm0 + arow) * K + acolsw;
  const u16* Bg = B + (size_t)(bn0 + arow) * K + acolsw;

  for (int k0 = kbeg; k0 < kend; k0 += 64) {
    __syncthreads();
#pragma unroll
    for (int r = 0; r < 2; r++) {
      async16(Ag + (size_t)(r * 32) * K + k0, As + t * 8 + r * 2048);
      async16(Bg + (size_t)(r * 32) * K + k0, Bs + t * 8 + r * 2048);
    }
    __syncthreads();
#pragma unroll
    for (int kk = 0; kk < 64; kk += 32) {
      bf16x8 af[2], bf[2];
#pragma unroll
      for (int mi = 0; mi < 2; mi++) {
        int row = wm + mi * 16 + lr;
        int c = (kk >> 3) + kg;
        af[mi] = load8(&As[row * 64 + ((c ^ (row & 7)) << 3)]);
      }
#pragma unroll
      for (int ni = 0; ni < 2; ni++) {
        int row = wn + ni * 16 + lr;
        int c = (kk >> 3) + kg;
        bf[ni] = load8(&Bs[row * 64 + ((c ^ (row & 7)) << 3)]);
      }
#pragma unroll
      for (int mi = 0; mi < 2; mi++)
#pragma unroll
        for (int ni = 0; ni < 2; ni++)
          acc[mi][ni] = __builtin_amdgcn_mfma_f32_16x16x32_bf16(
              af[mi], bf[ni], acc[mi][ni], 0, 0, 0);
    }
  }
  // scrambled, thread-contiguous partial store (fully coalesced)
  f32x4* P4 = (f32x4*)(P + ((size_t)z * NB1 + tri) * (T1 * T1) + t * 16);
#pragma unroll
  for (int ni = 0; ni < 2; ni++)
#pragma unroll
    for (int mi = 0; mi < 2; mi++) P4[ni * 2 + mi] = acc[mi][ni];
}

// combine 3 slices -> LDS tile -> A1 both triangles (diag + adj applied)
__global__ __launch_bounds__(256) void k_comb(const float* __restrict__ P,
                                              const float* __restrict__ adj,
                                              u16* __restrict__ A1) {
  const int tri = blockIdx.x;
  int bi, bj;
  tri_decode(tri, NT1, bi, bj);
  __shared__ float tile[T1][T1 + 1];
  const int bm0 = bi * T1, bn0 = bj * T1;
  const int t = threadIdx.x;
  const bool diagb = (bi == bj);
  const int lane = t & 63, lr = lane & 15, kg = lane >> 4;
  const int wave = t >> 6, wm = (wave >> 1) * 32, wn = (wave & 1) * 32;

  const f32x4* P4 = (const f32x4*)(P + (size_t)tri * (T1 * T1) + t * 16);
  const size_t SL = (size_t)NB1 * (T1 * T1) / 4;  // slice stride in f32x4
#pragma unroll
  for (int ni = 0; ni < 2; ni++) {
#pragma unroll
    for (int mi = 0; mi < 2; mi++) {
      f32x4 s = P4[ni * 2 + mi];
      f32x4 s1 = P4[SL + ni * 2 + mi];
      f32x4 s2 = P4[2 * SL + ni * 2 + mi];
      s = s + s1 + s2;
      const int cil = wm + mi * 16 + kg * 4;
      const int cjl = wn + ni * 16 + lr;
#pragma unroll
      for (int r = 0; r < 4; r++) tile[cil + r][cjl] = s[r];
    }
  }
  __syncthreads();
#pragma unroll
  for (int q = 0; q < 4; q++) {
    int idx = t + 256 * q;          // 1024 chunks of 4
    int row = idx >> 4, c4 = (idx & 15) * 4;
    size_t off = (size_t)(bm0 + row) * NN + bn0 + c4;
    float4 av = *(const float4*)(adj + off);
    float avv[4] = {av.x, av.y, av.z, av.w};
    union { u16 h[4]; uint2 u; } o;
#pragma unroll
    for (int j = 0; j < 4; j++) {
      float sv = tile[row][c4 + j];
      if (diagb && (c4 + j == row)) sv = 1.0f;
      o.h[j] = f2b(sv * avv[j]);
    }
    *(uint2*)(A1 + off) = o.u;
    if (!diagb) {
      size_t off2 = (size_t)(bn0 + row) * NN + bm0 + c4;
      float4 av2 = *(const float4*)(adj + off2);
      float a2[4] = {av2.x, av2.y, av2.z, av2.w};
      union { u16 h[4]; uint2 u; } o2;
#pragma unroll
      for (int j = 0; j < 4; j++) o2.h[j] = f2b(tile[c4 + j][row] * a2[j]);
      *(uint2*)(A1 + off2) = o2.u;
    }
  }
}

// ---------------- edge layer: 96x96 dense-triangular, bf16 out + colmax ----------------
// 2080 blocks (8.1/CU queued). wave w: 48x48 subtile, acc 3x3 (36 AGPR).
__global__ __launch_bounds__(256) void gemm_sym2(const u16* __restrict__ A,
                                                 const u16* __restrict__ B,
                                                 const float* __restrict__ adj,
                                                 u16* __restrict__ C,
                                                 u32* __restrict__ colmax) {
  const int L = (blockIdx.x & 7) * (NB2 / 8) + (blockIdx.x >> 3);
  int bi, bj;
  tri_decode(L, NT2, bi, bj);
  __shared__ union {
    u16 buf[2 * T2 * 64];   // staging (24 KB)
    u16 mir[T2 * MS2];      // epilogue mirror (19.2 KB)
  } sh;
  __shared__ u32 cmaxN[T2];
  __shared__ u32 cmaxM[T2];
  const int bm0 = bi * T2, bn0 = bj * T2;
  const int t = threadIdx.x, lane = t & 63;
  const int lr = lane & 15, kg = lane >> 4;
  const int wave = t >> 6;
  const int wm = (wave >> 1) * 48, wn = (wave & 1) * 48;
  const int K = NN;
  const bool diagb = (bi == bj);
  if (t < T2) { cmaxN[t] = 0u; cmaxM[t] = 0u; }

  f32x4 acc[3][3];
#pragma unroll
  for (int i = 0; i < 3; i++)
#pragma unroll
    for (int j = 0; j < 3; j++) acc[i][j] = (f32x4){0.f, 0.f, 0.f, 0.f};

  u16* As = sh.buf;
  u16* Bs = sh.buf + T2 * 64;
  const int arow = t >> 3;
  const int acolsw = (((t & 7) ^ (arow & 7)) * 8);
  const u16* Ag = A + (size_t)(bm0 + arow) * K + acolsw;
  const u16* Bg = B + (size_t)(bn0 + arow) * K + acolsw;

  for (int k0 = 0; k0 < K; k0 += 64) {
    __syncthreads();
#pragma unroll
    for (int r = 0; r < 3; r++) {
      async16(Ag + (size_t)(r * 32) * K + k0, As + t * 8 + r * 2048);
      async16(Bg + (size_t)(r * 32) * K + k0, Bs + t * 8 + r * 2048);
    }
    __syncthreads();
#pragma unroll
    for (int kk = 0; kk < 64; kk += 32) {
      bf16x8 af[3], bf[3];
#pragma unroll
      for (int mi = 0; mi < 3; mi++) {
        int row = wm + mi * 16 + lr;
        int c = (kk >> 3) + kg;
        af[mi] = load8(&As[row * 64 + ((c ^ (row & 7)) << 3)]);
      }
#pragma unroll
      for (int ni = 0; ni < 3; ni++) {
        int row = wn + ni * 16 + lr;
        int c = (kk >> 3) + kg;
        bf[ni] = load8(&Bs[row * 64 + ((c ^ (row & 7)) << 3)]);
      }
#pragma unroll
      for (int mi = 0; mi < 3; mi++)
#pragma unroll
        for (int ni = 0; ni < 3; ni++)
          acc[mi][ni] = __builtin_amdgcn_mfma_f32_16x16x32_bf16(
              af[mi], bf[ni], acc[mi][ni], 0, 0, 0);
    }
  }

  __syncthreads();  // staging reads done before mir alias is written

  // upper tile from registers (+ raw v staged transposed into mir)
#pragma unroll
  for (int ni = 0; ni < 3; ni++) {
    const int cjl = wn + ni * 16 + lr;
    const int cj = bn0 + cjl;
    float cm = 0.f;
#pragma unroll
    for (int mi = 0; mi < 3; mi++) {
#pragma unroll
      for (int r = 0; r < 4; r++) {
        const int cil = wm + mi * 16 + kg * 4 + r;
        const int ci = bm0 + cil;
        float v = acc[mi][ni][r];
        if (ci == cj) v = 1.0f;
        float w = v * adj[(size_t)ci * NE + cj];
        C[(size_t)ci * NE + cj] = f2b(w);
        cm = fmaxf(cm, w);
        if (!diagb) sh.mir[cjl * MS2 + cil] = f2b(v);
      }
    }
    atomicMax(&cmaxN[cjl], __float_as_uint(cm));
  }

  if (!diagb) {
    __syncthreads();
    // mirror tile, coalesced uint2 chunks: 2304 chunks / 256 threads = 9
#pragma unroll
    for (int q = 0; q < 9; q++) {
      int idx = t + 256 * q;
      int row = idx / 24, c4 = (idx - row * 24) * 4;
      union { uint2 u; u16 s[4]; } wv;
      wv.u = *(const uint2*)&sh.mir[row * MS2 + c4];
      float4 av = *(const float4*)&adj[(size_t)(bn0 + row) * NE + bm0 + c4];
      float a[4] = {av.x, av.y, av.z, av.w};
      union { u16 h[4]; uint2 u; } o;
#pragma unroll
      for (int j = 0; j < 4; j++) {
        float w = b2f(wv.s[j]) * a[j];
        o.h[j] = f2b(w);
        atomicMax(&cmaxM[c4 + j], __float_as_uint(w));
      }
      *(uint2*)&C[(size_t)(bn0 + row) * NE + bm0 + c4] = o.u;
    }
  }

  __syncthreads();
  if (t < T2) {
    atomicMax(&colmax[bn0 + t], cmaxN[t]);
    if (!diagb) atomicMax(&colmax[bm0 + t], cmaxM[t]);
  }
}

// ---------------- thin MFMA gemms: split-K across blocks, atomicAdd ----------------

// Hv_out += A1 @ X ; grid 512: m0 = (bx&127)*16, z = bx>>7 (K quarter)
__global__ __launch_bounds__(512) void k_hv(const u16* __restrict__ A1,
                                            const u16* __restrict__ Xt,
                                            float* __restrict__ out) {
  __shared__ float red[8 * 1024];
  const int t = threadIdx.x, wave = t >> 6, lane = t & 63;
  const int lr = lane & 15, kg = lane >> 4;
  const int bx = blockIdx.x;
  const int m0 = (bx & 127) * 16, z = bx >> 7;
  const int K = NN;
  f32x4 acc[4];
#pragma unroll
  for (int i = 0; i < 4; i++) acc[i] = (f32x4){0.f, 0.f, 0.f, 0.f};
  const int kbeg = z * 512 + wave * 64, kend = kbeg + 64;
  for (int k = kbeg; k < kend; k += 32) {
    bf16x8 af = load8(&A1[(size_t)(m0 + lr) * K + k + kg * 8]);
#pragma unroll
    for (int ni = 0; ni < 4; ni++) {
      bf16x8 bfr = load8(&Xt[(size_t)(ni * 16 + lr) * K + k + kg * 8]);
      acc[ni] = __builtin_amdgcn_mfma_f32_16x16x32_bf16(af, bfr, acc[ni], 0, 0, 0);
    }
  }
#pragma unroll
  for (int ni = 0; ni < 4; ni++)
#pragma unroll
    for (int r = 0; r < 4; r++)
      red[wave * 1024 + (kg * 4 + r) * 64 + ni * 16 + lr] = acc[ni][r];
  __syncthreads();
#pragma unroll
  for (int q = 0; q < 2; q++) {
    int e = t + 512 * q;
    int row = e >> 6, col = e & 63;
    float v = 0.f;
#pragma unroll
    for (int w = 0; w < 8; w++) v += red[w * 1024 + e];
    atomicAdd(&out[(size_t)(m0 + row) * DVOUT + col], v);
  }
}

// He_out += adjE @ Z ; grid 768: m0 = (bx%384)*16, z = bx/384 (K half)
__global__ __launch_bounds__(512) void k_he(const u16* __restrict__ adjE,
                                            const u16* __restrict__ Ztb,
                                            float* __restrict__ out) {
  __shared__ float red[8 * 256];
  const int t = threadIdx.x, wave = t >> 6, lane = t & 63;
  const int lr = lane & 15, kg = lane >> 4;
  const int bx = blockIdx.x;
  const int m0 = (bx % 384) * 16, z = bx / 384;
  const int K = NE;
  f32x4 acc = (f32x4){0.f, 0.f, 0.f, 0.f};
  const int kbeg = z * 3072 + wave * 384, kend = kbeg + 384;
  for (int k = kbeg; k < kend; k += 32) {
    bf16x8 af = load8(&adjE[(size_t)(m0 + lr) * K + k + kg * 8]);
    bf16x8 bfr = load8(&Ztb[(size_t)lr * K + k + kg * 8]);
    acc = __builtin_amdgcn_mfma_f32_16x16x32_bf16(af, bfr, acc, 0, 0, 0);
  }
#pragma unroll
  for (int r = 0; r < 4; r++)
    red[wave * 256 + (kg * 4 + r) * 16 + lr] = acc[r];
  __syncthreads();
  if (t < 256) {
    int row = t >> 4, col = t & 15;
    float v = 0.f;
#pragma unroll
    for (int w = 0; w < 8; w++) v += red[w * 256 + t];
    atomicAdd(&out[(size_t)(m0 + row) * DEOUT + col], v);
  }
}

// ---------------- launcher ----------------
extern "C" void kernel_launch(void* const* d_in, const int* in_sizes, int n_in,
                              void* d_out, int out_size, void* d_ws, size_t ws_size,
                              hipStream_t stream) {
  const float* H_v = (const float*)d_in[0];
  const float* H_e = (const float*)d_in[1];
  const float* adj_v = (const float*)d_in[2];
  const float* adj_e = (const float*)d_in[3];
  const float* T = (const float*)d_in[4];
  const float* W_v = (const float*)d_in[5];
  const float* b_v = (const float*)d_in[6];
  const float* p_v = (const float*)d_in[7];
  const float* W_e = (const float*)d_in[8];
  const float* b_e = (const float*)d_in[9];
  const float* p_e = (const float*)d_in[10];
  float* outHv = (float*)d_out;              // [2048,64]
  float* outHe = (float*)d_out + NN * DVOUT; // [6144,16]

  char* ws = (char*)d_ws;
  u16* Tb   = (u16*)(ws + 0);           // 25165824
  u16* Tbs  = (u16*)(ws + 25165824);    // 25165824
  u16* Tt   = (u16*)(ws + 50331648);    // 25165824
  u16* Tts  = (u16*)(ws + 75497472);    // 25165824
  u16* adjE = (u16*)(ws + 100663296);   // 75497472
  u16* A1   = (u16*)(ws + 176160768);   // 8388608
  u16* Xt   = (u16*)(ws + 184549376);   // 262144
  u16* Ztb  = (u16*)(ws + 184811520);   // 196608
  float* de = (float*)(ws + 185008128); // 24576
  float* dv = (float*)(ws + 185032704); // 8192
  u32* cmax = (u32*)(ws + 185040896);   // 24576
  // P (split-K fp32 partials, 3*528*4096*4 = 25,952,256 B) at offset
  // 50331648, OVERLAPPING Tt/Tts: P is dead after k_comb, which runs
  // before k_tt writes those buffers.
  float* P = (float*)(ws + 50331648);

  k_de<<<NE / 256, 256, 0, stream>>>(H_e, p_v, de);
  k_tb<<<(NN * (size_t)NE) / 8 / 256, 256, 0, stream>>>(T, de, Tb, Tbs);
  k_x<<<dim3(NN / 256, DVOUT), 256, 0, stream>>>(H_v, W_v, Xt);
  gemm_sym1<<<3 * NB1, 256, 0, stream>>>(Tbs, Tb, P);
  k_comb<<<NB1, 256, 0, stream>>>(P, adj_v, A1);
  k_bias<<<(NN * DVOUT + NE * DEOUT) / 256, 256, 0, stream>>>(b_v, b_e, outHv, outHe);
  k_hv<<<512, 512, 0, stream>>>(A1, Xt, outHv);
  k_dv<<<NN / 256, 256, 0, stream>>>(outHv, p_e, dv);
  k_tt<<<dim3(NE / 32, NN / 32), dim3(32, 8), 0, stream>>>(T, dv, Tt, Tts);
  hipMemsetAsync(cmax, 0, NE * sizeof(u32), stream);
  gemm_sym2<<<NB2, 256, 0, stream>>>(Tts, Tt, adj_e, adjE, cmax);
  k_zt<<<NE / 256, 256, 0, stream>>>(H_e, W_e, cmax, Ztb);
  k_he<<<768, 512, 0, stream>>>(adjE, Ztb, outHe);
}